// Round 1
// baseline (1006.927 us; speedup 1.0000x reference)
//
#include <hip/hip_runtime.h>
#include <math.h>

// ---------------- problem constants (ANI-2x) ----------------
constexpr int SPEC = 7;          // species
constexpr int DAEV = 1008;       // AEV dim = 7*16 + 28*32
constexpr int RADN = 112;        // radial section width
constexpr int H1W = 256, H2W = 192, H3W = 160;
constexpr int MENS = 8;          // ensemble size
constexpr float ALPHA = 0.1f;    // celu alpha
constexpr float RCR_ = 5.2f, RCA_ = 3.5f;
constexpr float ETAR = 19.7f, ETAA = 12.5f, ZETA_ = 14.1f;
constexpr float PIF = 3.14159265358979323846f;

constexpr int TILE = 64;
constexpr int KTILE = 16;

enum { MODE_FWD = 0, MODE_BWD = 1, MODE_PLAIN = 2 };

// ---------------- species-list build ----------------
__global__ __launch_bounds__(256) void build_lists_k(
    const int* __restrict__ sgp, int* __restrict__ counts,
    int* __restrict__ lists, int N)
{
    int n = blockIdx.x * blockDim.x + threadIdx.x;
    if (n >= N) return;
    int g = sgp[n];
    if (g >= 0) {
        int p = atomicAdd(&counts[g], 1);
        lists[g * N + p] = n;
    }
}

// ---------------- AEV radial forward ----------------
__global__ __launch_bounds__(256) void radial_fwd_k(
    const int* __restrict__ ai12, const int* __restrict__ spec,
    const float* __restrict__ coord, float* __restrict__ aev, int P)
{
    int p = blockIdx.x * blockDim.x + threadIdx.x;
    if (p >= P) return;
    int i = ai12[p], j = ai12[P + p];
    float dx = coord[3 * j + 0] - coord[3 * i + 0];
    float dy = coord[3 * j + 1] - coord[3 * i + 1];
    float dz = coord[3 * j + 2] - coord[3 * i + 2];
    float d = sqrtf(dx * dx + dy * dy + dz * dz);
    float fc = (d < RCR_) ? (0.5f * cosf(PIF * d / RCR_) + 0.5f) : 0.f;
    int spi = spec[i], spj = spec[j];
    float* bi = aev + (size_t)i * DAEV + spj * 16;
    float* bj = aev + (size_t)j * DAEV + spi * 16;
    #pragma unroll
    for (int k = 0; k < 16; ++k) {
        float sh = 0.8f + 0.275f * k;
        float t = d - sh;
        float v = 0.25f * expf(-ETAR * t * t) * fc;
        atomicAdd(bi + k, v);
        atomicAdd(bj + k, v);
    }
}

// ---------------- AEV angular forward ----------------
__global__ __launch_bounds__(256) void angular_fwd_k(
    const int* __restrict__ tri, const int* __restrict__ spec,
    const float* __restrict__ coord, float* __restrict__ aev, int T)
{
    int t = blockIdx.x * blockDim.x + threadIdx.x;
    if (t >= T) return;
    int c = tri[t], a = tri[T + t], b = tri[2 * T + t];
    float cx = coord[3 * c], cy = coord[3 * c + 1], cz = coord[3 * c + 2];
    float v1x = coord[3 * a] - cx, v1y = coord[3 * a + 1] - cy, v1z = coord[3 * a + 2] - cz;
    float v2x = coord[3 * b] - cx, v2y = coord[3 * b + 1] - cy, v2z = coord[3 * b + 2] - cz;
    float d1 = sqrtf(v1x * v1x + v1y * v1y + v1z * v1z);
    float d2 = sqrtf(v2x * v2x + v2y * v2y + v2z * v2z);
    float u = v1x * v2x + v1y * v2y + v1z * v2z;
    float ca = 0.95f * u / (d1 * d2);
    float sa = sqrtf(fmaxf(1.f - ca * ca, 0.f));
    float fc1 = (d1 < RCA_) ? (0.5f * cosf(PIF * d1 / RCA_) + 0.5f) : 0.f;
    float fc2 = (d2 < RCA_) ? (0.5f * cosf(PIF * d2 / RCA_) + 0.5f) : 0.f;
    float fcj = fc1 * fc2;
    float savg = 0.5f * (d1 + d2);
    int s1 = spec[a], s2 = spec[b];
    int lo = min(s1, s2), hi = max(s1, s2);
    int pidx = lo * SPEC - (lo * (lo - 1)) / 2 + (hi - lo);
    float* ob = aev + (size_t)c * DAEV + RADN + pidx * 32;
    const float CZ[4] = {0.92387953f, 0.38268343f, -0.38268343f, -0.92387953f};
    const float SZ[4] = {0.38268343f, 0.92387953f, 0.92387953f, 0.38268343f};
    float f1[4];
    #pragma unroll
    for (int zz = 0; zz < 4; ++zz) {
        float cd = ca * CZ[zz] + sa * SZ[zz];               // cos(ang - shz), exact identity
        float base = fmaxf(0.5f * (1.f + cd), 0.f);
        f1[zz] = powf(base, ZETA_);
    }
    #pragma unroll
    for (int q = 0; q < 8; ++q) {
        float sh = 0.8f + 0.3375f * q;
        float tq = savg - sh;
        float f2 = expf(-ETAA * tq * tq);
        float b2 = 2.f * f2 * fcj;
        #pragma unroll
        for (int zz = 0; zz < 4; ++zz)
            atomicAdd(ob + q * 4 + zz, b2 * f1[zz]);
    }
}

// ---------------- generic tiled fp32 GEMM with row gather ----------------
// C[atom, col] = sum_k A[atom, k] * B[k, col]   (+bias, celu)   MODE_FWD
// C[atom, col] = (sum_k ...) * celu'(C_old)                     MODE_BWD (in-place)
// C[atom, col] = sum_k ...                                      MODE_PLAIN
// BT: B stored [col][k].  MCONCAT: K = 8*256 concat over ensemble m (L1 bwd).
template<int MODE, bool BT, bool MCONCAT>
__global__ __launch_bounds__(256) void gemm_k(
    const float* __restrict__ A, const float* __restrict__ B,
    const float* __restrict__ bias, float* __restrict__ C,
    const int* __restrict__ lists, const int* __restrict__ counts,
    int N, int K, int H, int lda, int ldb, int ldc,
    size_t amOff, size_t bzOff, size_t cmOff)
{
    __shared__ float As[KTILE][TILE];
    __shared__ float Bs[KTILE][TILE];
    __shared__ int atomsS[TILE];

    const int z = blockIdx.z;
    int m, s;
    if (MCONCAT) { s = z; m = 0; } else { m = z / SPEC; s = z - m * SPEC; }
    const int cnt = counts[s];
    const int row0 = blockIdx.y * TILE;
    if (row0 >= cnt) return;
    const int col0 = blockIdx.x * TILE;
    const int tid = threadIdx.x;

    const float* Ab = A + (size_t)m * amOff;
    const float* Bb = MCONCAT ? (B + (size_t)s * ((size_t)DAEV * H1W))
                              : (B + (size_t)z * bzOff);
    float* Cb = C + (size_t)m * cmOff;

    if (tid < TILE) {
        int r = row0 + tid;
        atomsS[tid] = (r < cnt) ? lists[s * N + r] : -1;
    }
    __syncthreads();

    const int rowA = tid >> 2;
    const int kA0 = (tid & 3) * 4;
    const int atomA = atomsS[rowA];
    const int kB = tid >> 4;
    const int colB0 = (tid & 15) * 4;
    const int colT = tid >> 2;
    const int kT0 = (tid & 3) * 4;
    const bool colEdge = (col0 + TILE > H);

    float acc[4][4] = {{0.f}};

    for (int k0 = 0; k0 < K; k0 += KTILE) {
        // stage A (gathered rows; zeros for invalid rows)
        float4 av = make_float4(0.f, 0.f, 0.f, 0.f);
        if (atomA >= 0) {
            int k = k0 + kA0;
            if (MCONCAT) {
                const float* p = Ab + (size_t)(k >> 8) * ((size_t)N * H1W)
                                    + (size_t)atomA * H1W + (k & 255);
                av = *(const float4*)p;
            } else {
                av = *(const float4*)(Ab + (size_t)atomA * lda + k);
            }
        }
        As[kA0 + 0][rowA] = av.x;
        As[kA0 + 1][rowA] = av.y;
        As[kA0 + 2][rowA] = av.z;
        As[kA0 + 3][rowA] = av.w;

        // stage B
        if (!BT) {
            int k = k0 + kB;
            float4 bv;
            if (!colEdge) {
                bv = *(const float4*)(Bb + (size_t)k * ldb + (col0 + colB0));
            } else {
                float t0 = 0.f, t1 = 0.f, t2 = 0.f, t3 = 0.f;
                int cb = col0 + colB0;
                if (cb + 0 < H) t0 = Bb[(size_t)k * ldb + cb + 0];
                if (cb + 1 < H) t1 = Bb[(size_t)k * ldb + cb + 1];
                if (cb + 2 < H) t2 = Bb[(size_t)k * ldb + cb + 2];
                if (cb + 3 < H) t3 = Bb[(size_t)k * ldb + cb + 3];
                bv = make_float4(t0, t1, t2, t3);
            }
            *(float4*)&Bs[kB][colB0] = bv;
        } else {
            int col = col0 + colT;
            int k = k0 + kT0;
            float4 bv = make_float4(0.f, 0.f, 0.f, 0.f);
            if (col < H) {
                const float* p;
                if (MCONCAT) {
                    p = B + ((size_t)(k >> 8) * SPEC + s) * ((size_t)DAEV * H1W)
                          + (size_t)col * H1W + (k & 255);
                } else {
                    p = Bb + (size_t)col * ldb + k;
                }
                bv = *(const float4*)p;
            }
            Bs[kT0 + 0][colT] = bv.x;
            Bs[kT0 + 1][colT] = bv.y;
            Bs[kT0 + 2][colT] = bv.z;
            Bs[kT0 + 3][colT] = bv.w;
        }
        __syncthreads();

        #pragma unroll
        for (int kk = 0; kk < KTILE; ++kk) {
            float4 a = *(const float4*)&As[kk][(tid >> 4) * 4];
            float4 b = *(const float4*)&Bs[kk][(tid & 15) * 4];
            acc[0][0] += a.x * b.x; acc[0][1] += a.x * b.y; acc[0][2] += a.x * b.z; acc[0][3] += a.x * b.w;
            acc[1][0] += a.y * b.x; acc[1][1] += a.y * b.y; acc[1][2] += a.y * b.z; acc[1][3] += a.y * b.w;
            acc[2][0] += a.z * b.x; acc[2][1] += a.z * b.y; acc[2][2] += a.z * b.z; acc[2][3] += a.z * b.w;
            acc[3][0] += a.w * b.x; acc[3][1] += a.w * b.y; acc[3][2] += a.w * b.z; acc[3][3] += a.w * b.w;
        }
        __syncthreads();
    }

    const int ty = tid >> 4, tx = tid & 15;
    const float* brow = (MODE == MODE_FWD) ? (bias + (size_t)z * H) : nullptr;
    for (int i = 0; i < 4; ++i) {
        int rl = ty * 4 + i;
        int atom = atomsS[rl];
        if (atom < 0) continue;
        float* crow = Cb + (size_t)atom * ldc;
        for (int j = 0; j < 4; ++j) {
            int col = col0 + tx * 4 + j;
            if (col >= H) continue;
            float v = acc[i][j];
            if (MODE == MODE_FWD) {
                v += brow[col];
                v = (v > 0.f) ? v : ALPHA * expm1f(v * (1.f / ALPHA));
            } else if (MODE == MODE_BWD) {
                float h = crow[col];
                float D = (h > 0.f) ? 1.f : (h * (1.f / ALPHA) + 1.f);  // celu'(z) from h
                v *= D;
            }
            crow[col] = v;
        }
    }
}

// ---------------- layer-4 dot + energy + start of backward ----------------
__global__ __launch_bounds__(256) void l4_k(
    float* __restrict__ H3buf, const float* __restrict__ W4,
    const float* __restrict__ b4, const int* __restrict__ lists,
    const int* __restrict__ counts, float* __restrict__ Eout, int N)
{
    const int z = blockIdx.y;
    const int m = z / SPEC, s = z - m * SPEC;
    const int cnt = counts[s];
    const int sub = threadIdx.x >> 3;
    const int l8 = threadIdx.x & 7;
    const int row = blockIdx.x * 32 + sub;

    __shared__ float bsum;
    if (threadIdx.x == 0) bsum = 0.f;
    __syncthreads();

    if (row < cnt) {
        int atom = lists[s * N + row];
        float* hb = H3buf + ((size_t)m * N + atom) * H3W;
        const float* w4 = W4 + (size_t)z * H3W;
        float sum = 0.f;
        for (int k = l8; k < H3W; k += 8) {
            float h = hb[k];
            float w = w4[k];
            sum += h * w;
            float D = (h > 0.f) ? 1.f : (h * 10.f + 1.f);
            hb[k] = 0.125f * w * D;          // dh3 (already scaled by ensemble mean)
        }
        sum += __shfl_xor(sum, 1);
        sum += __shfl_xor(sum, 2);
        sum += __shfl_xor(sum, 4);
        if (l8 == 0) atomicAdd(&bsum, sum + b4[z]);
    }
    __syncthreads();
    if (threadIdx.x == 0) atomicAdd(Eout, 0.125f * bsum);
}

// ---------------- AEV radial backward ----------------
__global__ __launch_bounds__(256) void radial_bwd_k(
    const int* __restrict__ ai12, const int* __restrict__ spec,
    const float* __restrict__ coord, const float* __restrict__ daev,
    float* __restrict__ grad, int P)
{
    int p = blockIdx.x * blockDim.x + threadIdx.x;
    if (p >= P) return;
    int i = ai12[p], j = ai12[P + p];
    float dx = coord[3 * j + 0] - coord[3 * i + 0];
    float dy = coord[3 * j + 1] - coord[3 * i + 1];
    float dz = coord[3 * j + 2] - coord[3 * i + 2];
    float d = sqrtf(dx * dx + dy * dy + dz * dz);
    float fc, dfc;
    if (d < RCR_) {
        float ph = PIF * d / RCR_;
        fc = 0.5f * cosf(ph) + 0.5f;
        dfc = -0.5f * sinf(ph) * (PIF / RCR_);
    } else { fc = 0.f; dfc = 0.f; }
    int spi = spec[i], spj = spec[j];
    const float* gi = daev + (size_t)i * DAEV + spj * 16;
    const float* gj = daev + (size_t)j * DAEV + spi * 16;
    float gs = 0.f;
    #pragma unroll
    for (int k = 0; k < 16; ++k) {
        float sh = 0.8f + 0.275f * k;
        float t = d - sh;
        float ex = expf(-ETAR * t * t);
        float g = gi[k] + gj[k];
        gs += g * 0.25f * ex * (dfc - 2.f * ETAR * t * fc);
    }
    float invd = 1.f / d;
    float gx = gs * dx * invd, gy = gs * dy * invd, gz = gs * dz * invd;
    atomicAdd(&grad[3 * j + 0], gx);  atomicAdd(&grad[3 * j + 1], gy);  atomicAdd(&grad[3 * j + 2], gz);
    atomicAdd(&grad[3 * i + 0], -gx); atomicAdd(&grad[3 * i + 1], -gy); atomicAdd(&grad[3 * i + 2], -gz);
}

// ---------------- AEV angular backward ----------------
__global__ __launch_bounds__(256) void angular_bwd_k(
    const int* __restrict__ tri, const int* __restrict__ spec,
    const float* __restrict__ coord, const float* __restrict__ daev,
    float* __restrict__ grad, int T)
{
    int t = blockIdx.x * blockDim.x + threadIdx.x;
    if (t >= T) return;
    int c = tri[t], a = tri[T + t], b = tri[2 * T + t];
    float cx = coord[3 * c], cy = coord[3 * c + 1], cz = coord[3 * c + 2];
    float v1x = coord[3 * a] - cx, v1y = coord[3 * a + 1] - cy, v1z = coord[3 * a + 2] - cz;
    float v2x = coord[3 * b] - cx, v2y = coord[3 * b + 1] - cy, v2z = coord[3 * b + 2] - cz;
    float d1 = sqrtf(v1x * v1x + v1y * v1y + v1z * v1z);
    float d2 = sqrtf(v2x * v2x + v2y * v2y + v2z * v2z);
    float u = v1x * v2x + v1y * v2y + v1z * v2z;
    float inv12 = 1.f / (d1 * d2);
    float ca = 0.95f * u * inv12;
    float sa = sqrtf(fmaxf(1.f - ca * ca, 1e-12f));
    float fc1, dfc1, fc2, dfc2;
    if (d1 < RCA_) {
        float ph = PIF * d1 / RCA_;
        fc1 = 0.5f * cosf(ph) + 0.5f;
        dfc1 = -0.5f * sinf(ph) * (PIF / RCA_);
    } else { fc1 = 0.f; dfc1 = 0.f; }
    if (d2 < RCA_) {
        float ph = PIF * d2 / RCA_;
        fc2 = 0.5f * cosf(ph) + 0.5f;
        dfc2 = -0.5f * sinf(ph) * (PIF / RCA_);
    } else { fc2 = 0.f; dfc2 = 0.f; }
    float fcj = fc1 * fc2;
    float savg = 0.5f * (d1 + d2);
    int s1 = spec[a], s2 = spec[b];
    int lo = min(s1, s2), hi = max(s1, s2);
    int pidx = lo * SPEC - (lo * (lo - 1)) / 2 + (hi - lo);
    const float* gb = daev + (size_t)c * DAEV + RADN + pidx * 32;
    const float CZ[4] = {0.92387953f, 0.38268343f, -0.38268343f, -0.92387953f};
    const float SZ[4] = {0.38268343f, 0.92387953f, 0.92387953f, 0.38268343f};
    float f1[4], df1[4];
    #pragma unroll
    for (int zz = 0; zz < 4; ++zz) {
        float cd = ca * CZ[zz] + sa * SZ[zz];   // cos(ang - shz)
        float sd = sa * CZ[zz] - ca * SZ[zz];   // sin(ang - shz)
        float base = fmaxf(0.5f * (1.f + cd), 0.f);
        float pm1 = powf(base, ZETA_ - 1.f);
        f1[zz] = pm1 * base;
        df1[zz] = ZETA_ * pm1 * (-0.5f * sd);   // d f1 / d ang
    }
    float A_ = 0.f, B_ = 0.f, Cc = 0.f;
    #pragma unroll
    for (int q = 0; q < 8; ++q) {
        float sh = 0.8f + 0.3375f * q;
        float tq = savg - sh;
        float f2 = expf(-ETAA * tq * tq);
        float df2 = -ETAA * tq * f2;            // d f2 / d (d1+d2)
        #pragma unroll
        for (int zz = 0; zz < 4; ++zz) {
            float G2 = 2.f * gb[q * 4 + zz];
            A_ += G2 * f2 * df1[zz];
            B_ += G2 * df2 * f1[zz];
            Cc += G2 * f2 * f1[zz];
        }
    }
    A_ *= fcj; B_ *= fcj;
    float C1 = Cc * dfc1 * fc2;
    float C2 = Cc * fc1 * dfc2;
    float cA = -A_ / sa;                        // A * dang/dcos
    float k12 = cA * 0.95f * inv12;
    float coef1 = (cA * (-ca) / d1 + B_ + C1) / d1;
    float coef2 = (cA * (-ca) / d2 + B_ + C2) / d2;
    float g1x = coef1 * v1x + k12 * v2x;
    float g1y = coef1 * v1y + k12 * v2y;
    float g1z = coef1 * v1z + k12 * v2z;
    float g2x = coef2 * v2x + k12 * v1x;
    float g2y = coef2 * v2y + k12 * v1y;
    float g2z = coef2 * v2z + k12 * v1z;
    atomicAdd(&grad[3 * a + 0], g1x); atomicAdd(&grad[3 * a + 1], g1y); atomicAdd(&grad[3 * a + 2], g1z);
    atomicAdd(&grad[3 * b + 0], g2x); atomicAdd(&grad[3 * b + 1], g2y); atomicAdd(&grad[3 * b + 2], g2z);
    atomicAdd(&grad[3 * c + 0], -(g1x + g2x));
    atomicAdd(&grad[3 * c + 1], -(g1y + g2y));
    atomicAdd(&grad[3 * c + 2], -(g1z + g2z));
}

// ---------------- finalize: forces out, SAE into E ----------------
__global__ __launch_bounds__(256) void finalize_k(
    const float* __restrict__ grad, const int* __restrict__ sgp,
    const float* __restrict__ sae, float* __restrict__ out, int N)
{
    int n = blockIdx.x * blockDim.x + threadIdx.x;
    __shared__ float bs;
    if (threadIdx.x == 0) bs = 0.f;
    __syncthreads();
    float v = 0.f;
    if (n < N) {
        out[1 + 3 * n + 0] = -grad[3 * n + 0];
        out[1 + 3 * n + 1] = -grad[3 * n + 1];
        out[1 + 3 * n + 2] = -grad[3 * n + 2];
        int g = sgp[n];
        if (g >= 0) v = sae[g];
    }
    atomicAdd(&bs, v);
    __syncthreads();
    if (threadIdx.x == 0) atomicAdd(out, bs);
}

// ---------------- host launch ----------------
extern "C" void kernel_launch(void* const* d_in, const int* in_sizes, int n_in,
                              void* d_out, int out_size, void* d_ws, size_t ws_size,
                              hipStream_t stream)
{
    (void)n_in; (void)out_size; (void)ws_size;
    const int* species = (const int*)d_in[0];
    const float* coords = (const float*)d_in[1];
    const int* ai12 = (const int*)d_in[2];
    const int* tri = (const int*)d_in[3];
    const int* sgp = (const int*)d_in[4];
    const float* W1 = (const float*)d_in[5];
    const float* b1 = (const float*)d_in[6];
    const float* W2 = (const float*)d_in[7];
    const float* b2 = (const float*)d_in[8];
    const float* W3 = (const float*)d_in[9];
    const float* b3 = (const float*)d_in[10];
    const float* W4 = (const float*)d_in[11];
    const float* b4 = (const float*)d_in[12];
    const float* sae = (const float*)d_in[13];
    float* out = (float*)d_out;

    const int N = in_sizes[0];
    const int P = in_sizes[2] / 2;
    const int T = in_sizes[3] / 3;

    float* ws = (float*)d_ws;
    size_t off = 0;
    float* aev  = ws + off; off += (size_t)N * DAEV;
    float* daev = ws + off; off += (size_t)N * DAEV;
    float* H1b  = ws + off; off += (size_t)MENS * N * H1W;
    float* H2b  = ws + off; off += (size_t)MENS * N * H2W;
    float* H3b  = ws + off; off += (size_t)MENS * N * H3W;
    float* grad = ws + off; off += (size_t)N * 3;
    int* counts = (int*)(ws + off); off += 8;
    int* lists  = (int*)(ws + off); off += (size_t)SPEC * N;

    hipMemsetAsync(aev, 0, (size_t)N * DAEV * 2 * sizeof(float), stream);  // aev + daev
    hipMemsetAsync(grad, 0, (size_t)N * 3 * sizeof(float), stream);
    hipMemsetAsync(counts, 0, 8 * sizeof(int), stream);
    hipMemsetAsync(d_out, 0, sizeof(float), stream);

    build_lists_k<<<(N + 255) / 256, 256, 0, stream>>>(sgp, counts, lists, N);
    radial_fwd_k<<<(P + 255) / 256, 256, 0, stream>>>(ai12, species, coords, aev, P);
    angular_fwd_k<<<(T + 255) / 256, 256, 0, stream>>>(tri, species, coords, aev, T);

    const int rowTiles = (N + TILE - 1) / TILE;
    // L1 fwd: H1 = celu(AEV @ W1 + b1)
    gemm_k<MODE_FWD, false, false><<<dim3(4, rowTiles, 56), 256, 0, stream>>>(
        aev, W1, b1, H1b, lists, counts, N, DAEV, H1W, DAEV, H1W, H1W,
        0, (size_t)DAEV * H1W, (size_t)N * H1W);
    // L2 fwd
    gemm_k<MODE_FWD, false, false><<<dim3(3, rowTiles, 56), 256, 0, stream>>>(
        H1b, W2, b2, H2b, lists, counts, N, H1W, H2W, H1W, H2W, H2W,
        (size_t)N * H1W, (size_t)H1W * H2W, (size_t)N * H2W);
    // L3 fwd
    gemm_k<MODE_FWD, false, false><<<dim3(3, rowTiles, 56), 256, 0, stream>>>(
        H2b, W3, b3, H3b, lists, counts, N, H2W, H3W, H2W, H3W, H3W,
        (size_t)N * H2W, (size_t)H2W * H3W, (size_t)N * H3W);
    // L4: e = h3.W4 + b4 -> E; dh3 (in place in H3b)
    l4_k<<<dim3((N + 31) / 32, 56), 256, 0, stream>>>(H3b, W4, b4, lists, counts, out, N);
    // L3 bwd: dh2 = (dh3 @ W3^T) * celu'(z2)  (in place in H2b)
    gemm_k<MODE_BWD, true, false><<<dim3(3, rowTiles, 56), 256, 0, stream>>>(
        H3b, W3, nullptr, H2b, lists, counts, N, H3W, H2W, H3W, H3W, H2W,
        (size_t)N * H3W, (size_t)H2W * H3W, (size_t)N * H2W);
    // L2 bwd: dh1 = (dh2 @ W2^T) * celu'(z1)  (in place in H1b)
    gemm_k<MODE_BWD, true, false><<<dim3(4, rowTiles, 56), 256, 0, stream>>>(
        H2b, W2, nullptr, H1b, lists, counts, N, H2W, H1W, H2W, H2W, H1W,
        (size_t)N * H2W, (size_t)H1W * H2W, (size_t)N * H1W);
    // L1 bwd (m-concat K=2048): daev = sum_m dh1[m] @ W1[m,s]^T
    gemm_k<MODE_PLAIN, true, true><<<dim3(16, rowTiles, 7), 256, 0, stream>>>(
        H1b, W1, nullptr, daev, lists, counts, N, MENS * H1W, DAEV, H1W, H1W, DAEV,
        0, 0, 0);

    radial_bwd_k<<<(P + 255) / 256, 256, 0, stream>>>(ai12, species, coords, daev, grad, P);
    angular_bwd_k<<<(T + 255) / 256, 256, 0, stream>>>(tri, species, coords, daev, grad, T);
    finalize_k<<<(N + 255) / 256, 256, 0, stream>>>(grad, sgp, sae, out, N);
}

// Round 2
// 732.511 us; speedup vs baseline: 1.3746x; 1.3746x over previous
//
#include <hip/hip_runtime.h>
#include <math.h>

// ---------------- problem constants (ANI-2x) ----------------
constexpr int SPEC = 7;
constexpr int DAEV = 1008;
constexpr int RADN = 112;
constexpr int H1W = 256, H2W = 192, H3W = 160;
constexpr int MENS = 8;
constexpr float ALPHA = 0.1f;
constexpr float RCR_ = 5.2f, RCA_ = 3.5f;
constexpr float ETAR = 19.7f, ETAA = 12.5f, ZETA_ = 14.1f;
constexpr float PIF = 3.14159265358979323846f;

enum { MODE_FWD = 0, MODE_BWD = 1, MODE_PLAIN = 2 };

typedef _Float16 f16x8 __attribute__((ext_vector_type(8)));
typedef float f32x4 __attribute__((ext_vector_type(4)));

__device__ inline f32x4 mfma16(f16x8 a, f16x8 b, f32x4 c) {
    return __builtin_amdgcn_mfma_f32_16x16x32_f16(a, b, c, 0, 0, 0);
}

__device__ inline void cvt_hilo(const float* xv, f16x8& h, f16x8& l) {
    #pragma unroll
    for (int e = 0; e < 8; ++e) {
        _Float16 hh = (_Float16)xv[e];
        h[e] = hh;
        l[e] = (_Float16)(xv[e] - (float)hh);
    }
}

// ---------------- species-list build ----------------
__global__ __launch_bounds__(256) void build_lists_k(
    const int* __restrict__ sgp, int* __restrict__ counts,
    int* __restrict__ lists, int N)
{
    int n = blockIdx.x * blockDim.x + threadIdx.x;
    if (n >= N) return;
    int g = sgp[n];
    if (g >= 0) {
        int p = atomicAdd(&counts[g], 1);
        lists[g * N + p] = n;
    }
}

// ---------------- AEV radial forward ----------------
__global__ __launch_bounds__(256) void radial_fwd_k(
    const int* __restrict__ ai12, const int* __restrict__ spec,
    const float* __restrict__ coord, float* __restrict__ aev, int P)
{
    int p = blockIdx.x * blockDim.x + threadIdx.x;
    if (p >= P) return;
    int i = ai12[p], j = ai12[P + p];
    float dx = coord[3 * j + 0] - coord[3 * i + 0];
    float dy = coord[3 * j + 1] - coord[3 * i + 1];
    float dz = coord[3 * j + 2] - coord[3 * i + 2];
    float d = sqrtf(dx * dx + dy * dy + dz * dz);
    float fc = (d < RCR_) ? (0.5f * cosf(PIF * d / RCR_) + 0.5f) : 0.f;
    int spi = spec[i], spj = spec[j];
    float* bi = aev + (size_t)i * DAEV + spj * 16;
    float* bj = aev + (size_t)j * DAEV + spi * 16;
    #pragma unroll
    for (int k = 0; k < 16; ++k) {
        float sh = 0.8f + 0.275f * k;
        float t = d - sh;
        float v = 0.25f * expf(-ETAR * t * t) * fc;
        atomicAdd(bi + k, v);
        atomicAdd(bj + k, v);
    }
}

// ---------------- AEV angular forward ----------------
__global__ __launch_bounds__(256) void angular_fwd_k(
    const int* __restrict__ tri, const int* __restrict__ spec,
    const float* __restrict__ coord, float* __restrict__ aev, int T)
{
    int t = blockIdx.x * blockDim.x + threadIdx.x;
    if (t >= T) return;
    int c = tri[t], a = tri[T + t], b = tri[2 * T + t];
    float cx = coord[3 * c], cy = coord[3 * c + 1], cz = coord[3 * c + 2];
    float v1x = coord[3 * a] - cx, v1y = coord[3 * a + 1] - cy, v1z = coord[3 * a + 2] - cz;
    float v2x = coord[3 * b] - cx, v2y = coord[3 * b + 1] - cy, v2z = coord[3 * b + 2] - cz;
    float d1 = sqrtf(v1x * v1x + v1y * v1y + v1z * v1z);
    float d2 = sqrtf(v2x * v2x + v2y * v2y + v2z * v2z);
    float u = v1x * v2x + v1y * v2y + v1z * v2z;
    float ca = 0.95f * u / (d1 * d2);
    float sa = sqrtf(fmaxf(1.f - ca * ca, 0.f));
    float fc1 = (d1 < RCA_) ? (0.5f * cosf(PIF * d1 / RCA_) + 0.5f) : 0.f;
    float fc2 = (d2 < RCA_) ? (0.5f * cosf(PIF * d2 / RCA_) + 0.5f) : 0.f;
    float fcj = fc1 * fc2;
    float savg = 0.5f * (d1 + d2);
    int s1 = spec[a], s2 = spec[b];
    int lo = min(s1, s2), hi = max(s1, s2);
    int pidx = lo * SPEC - (lo * (lo - 1)) / 2 + (hi - lo);
    float* ob = aev + (size_t)c * DAEV + RADN + pidx * 32;
    const float CZ[4] = {0.92387953f, 0.38268343f, -0.38268343f, -0.92387953f};
    const float SZ[4] = {0.38268343f, 0.92387953f, 0.92387953f, 0.38268343f};
    float f1[4];
    #pragma unroll
    for (int zz = 0; zz < 4; ++zz) {
        float cd = ca * CZ[zz] + sa * SZ[zz];
        float base = fmaxf(0.5f * (1.f + cd), 0.f);
        f1[zz] = powf(base, ZETA_);
    }
    #pragma unroll
    for (int q = 0; q < 8; ++q) {
        float sh = 0.8f + 0.3375f * q;
        float tq = savg - sh;
        float f2 = expf(-ETAA * tq * tq);
        float b2 = 2.f * f2 * fcj;
        #pragma unroll
        for (int zz = 0; zz < 4; ++zz)
            atomicAdd(ob + q * 4 + zz, b2 * f1[zz]);
    }
}

// ---------------- MFMA fp16x3-split GEMM with row gather ----------------
// Block tile 64 rows x 128 cols, BK=32. 4 waves (2x2), wave tile 32x64.
// C = A @ B (+bias, celu) via hi/lo fp16 split: ab = ah*bh + ah*bl + al*bh.
// BT: B'[k][c] = Bsrc[c*ldb + k].  MCONCAT: K = MENS*H1W concat over m (L1 bwd).
template<int MODE, bool BT, bool MCONCAT>
__global__ __launch_bounds__(256) void mgemm_k(
    const float* __restrict__ A, const float* __restrict__ B,
    const float* __restrict__ bias, float* __restrict__ C,
    const int* __restrict__ lists, const int* __restrict__ counts,
    int N, int K, int H, int lda, int ldb, int ldc,
    size_t amOff, size_t bzOff, size_t cmOff)
{
    __shared__ f16x8 Ah[4][64];
    __shared__ f16x8 Al[4][64];
    __shared__ f16x8 Bh[4][128];
    __shared__ f16x8 Bl[4][128];
    __shared__ int atomsS[64];

    const int z = blockIdx.z;
    int m, sp_;
    if (MCONCAT) { sp_ = z; m = 0; } else { m = z / SPEC; sp_ = z - m * SPEC; }
    const int cnt = counts[sp_];
    const int row0 = blockIdx.y * 64;
    if (row0 >= cnt) return;
    const int col0 = blockIdx.x * 128;
    const int tid = threadIdx.x;

    const float* Ab = A + (size_t)m * amOff;
    const float* Bb = B + (size_t)z * bzOff;   // unused for MCONCAT

    if (tid < 64) {
        int r = row0 + tid;
        atomsS[tid] = (r < cnt) ? lists[sp_ * N + r] : -1;
    }

    // staging roles
    const int arow = tid >> 2, akq = tid & 3;       // A: 4 threads per row
    const int bkg = tid >> 6;                       // B: 4 k-groups, 2 cols/thread

    // compute roles
    const int wid = tid >> 6, lane = tid & 63;
    const int wr = wid >> 1, wc = wid & 1;
    const int fr = lane & 15, q = lane >> 4;

    f32x4 acc[2][4];
    #pragma unroll
    for (int mi = 0; mi < 2; ++mi)
        #pragma unroll
        for (int ni = 0; ni < 4; ++ni)
            acc[mi][ni] = (f32x4){0.f, 0.f, 0.f, 0.f};

    for (int k0 = 0; k0 < K; k0 += 32) {
        __syncthreads();
        // ---- stage A tile (64 x 32), gathered rows, fp32 -> f16 hi/lo ----
        {
            int atom = atomsS[arow];
            int kbase = k0 + akq * 8;
            float xv[8];
            if (atom >= 0 && kbase < K) {
                const float* p;
                if (MCONCAT)
                    p = Ab + (size_t)(kbase >> 8) * ((size_t)N * H1W)
                           + (size_t)atom * H1W + (kbase & 255);
                else
                    p = Ab + (size_t)atom * lda + kbase;
                float4 u0 = *(const float4*)p;
                float4 u1 = *(const float4*)(p + 4);
                xv[0] = u0.x; xv[1] = u0.y; xv[2] = u0.z; xv[3] = u0.w;
                xv[4] = u1.x; xv[5] = u1.y; xv[6] = u1.z; xv[7] = u1.w;
            } else {
                #pragma unroll
                for (int e = 0; e < 8; ++e) xv[e] = 0.f;
            }
            f16x8 h, l;
            cvt_hilo(xv, h, l);
            int slot = arow ^ (akq << 2);           // bank-spread swizzle
            Ah[akq][slot] = h;
            Al[akq][slot] = l;
        }
        // ---- stage B tile (32 x 128) ----
        {
            int kbase = k0 + bkg * 8;
            bool kok = (kbase < K);
            #pragma unroll
            for (int cc = 0; cc < 2; ++cc) {
                int c = (tid & 63) + cc * 64;
                int gc = col0 + c;
                float xv[8];
                if (kok && gc < H) {
                    if (BT) {
                        const float* p;
                        if (MCONCAT)
                            p = B + ((size_t)(kbase >> 8) * SPEC + sp_) * ((size_t)DAEV * H1W)
                                  + (size_t)gc * H1W + (kbase & 255);
                        else
                            p = Bb + (size_t)gc * ldb + kbase;
                        float4 u0 = *(const float4*)p;
                        float4 u1 = *(const float4*)(p + 4);
                        xv[0] = u0.x; xv[1] = u0.y; xv[2] = u0.z; xv[3] = u0.w;
                        xv[4] = u1.x; xv[5] = u1.y; xv[6] = u1.z; xv[7] = u1.w;
                    } else {
                        const float* p = Bb + (size_t)kbase * ldb + gc;
                        #pragma unroll
                        for (int j = 0; j < 8; ++j) xv[j] = p[(size_t)j * ldb];
                    }
                } else {
                    #pragma unroll
                    for (int e = 0; e < 8; ++e) xv[e] = 0.f;
                }
                f16x8 h, l;
                cvt_hilo(xv, h, l);
                Bh[bkg][c] = h;
                Bl[bkg][c] = l;
            }
        }
        __syncthreads();
        // ---- fragments + MFMA ----
        {
            f16x8 ah[2], av[2], bh[4], bv[4];
            #pragma unroll
            for (int mi = 0; mi < 2; ++mi) {
                int r = wr * 32 + mi * 16 + fr;
                int slot = r ^ (q << 2);
                ah[mi] = Ah[q][slot];
                av[mi] = Al[q][slot];
            }
            #pragma unroll
            for (int ni = 0; ni < 4; ++ni) {
                int c = wc * 64 + ni * 16 + fr;
                bh[ni] = Bh[q][c];
                bv[ni] = Bl[q][c];
            }
            #pragma unroll
            for (int mi = 0; mi < 2; ++mi)
                #pragma unroll
                for (int ni = 0; ni < 4; ++ni) {
                    acc[mi][ni] = mfma16(ah[mi], bv[ni], acc[mi][ni]);
                    acc[mi][ni] = mfma16(av[mi], bh[ni], acc[mi][ni]);
                    acc[mi][ni] = mfma16(ah[mi], bh[ni], acc[mi][ni]);
                }
        }
    }

    // ---- epilogue ----
    float* Cb = C + (size_t)m * cmOff;
    const float* brow = (MODE == MODE_FWD) ? (bias + (size_t)z * H) : nullptr;
    #pragma unroll
    for (int mi = 0; mi < 2; ++mi) {
        #pragma unroll
        for (int r = 0; r < 4; ++r) {
            int rl = wr * 32 + mi * 16 + q * 4 + r;
            int atom = atomsS[rl];
            if (atom < 0) continue;
            float* crow = Cb + (size_t)atom * ldc;
            #pragma unroll
            for (int ni = 0; ni < 4; ++ni) {
                int col = col0 + wc * 64 + ni * 16 + fr;
                if (col >= H) continue;
                float v = acc[mi][ni][r];
                if (MODE == MODE_FWD) {
                    v += brow[col];
                    v = (v > 0.f) ? v : ALPHA * expm1f(v * (1.f / ALPHA));
                } else if (MODE == MODE_BWD) {
                    float h = crow[col];
                    float D = (h > 0.f) ? 1.f : (h * (1.f / ALPHA) + 1.f);
                    v *= D;
                }
                crow[col] = v;
            }
        }
    }
}

// ---------------- layer-4 dot + energy + start of backward ----------------
__global__ __launch_bounds__(256) void l4_k(
    float* __restrict__ H3buf, const float* __restrict__ W4,
    const float* __restrict__ b4, const int* __restrict__ lists,
    const int* __restrict__ counts, float* __restrict__ Eout, int N)
{
    const int z = blockIdx.y;
    const int m = z / SPEC, s = z - m * SPEC;
    const int cnt = counts[s];
    const int sub = threadIdx.x >> 3;
    const int l8 = threadIdx.x & 7;
    const int row = blockIdx.x * 32 + sub;

    __shared__ float bsum;
    if (threadIdx.x == 0) bsum = 0.f;
    __syncthreads();

    if (row < cnt) {
        int atom = lists[s * N + row];
        float* hb = H3buf + ((size_t)m * N + atom) * H3W;
        const float* w4 = W4 + (size_t)z * H3W;
        float sum = 0.f;
        for (int k = l8; k < H3W; k += 8) {
            float h = hb[k];
            float w = w4[k];
            sum += h * w;
            float D = (h > 0.f) ? 1.f : (h * 10.f + 1.f);
            hb[k] = 0.125f * w * D;
        }
        sum += __shfl_xor(sum, 1);
        sum += __shfl_xor(sum, 2);
        sum += __shfl_xor(sum, 4);
        if (l8 == 0) atomicAdd(&bsum, sum + b4[z]);
    }
    __syncthreads();
    if (threadIdx.x == 0) atomicAdd(Eout, 0.125f * bsum);
}

// ---------------- AEV radial backward ----------------
__global__ __launch_bounds__(256) void radial_bwd_k(
    const int* __restrict__ ai12, const int* __restrict__ spec,
    const float* __restrict__ coord, const float* __restrict__ daev,
    float* __restrict__ grad, int P)
{
    int p = blockIdx.x * blockDim.x + threadIdx.x;
    if (p >= P) return;
    int i = ai12[p], j = ai12[P + p];
    float dx = coord[3 * j + 0] - coord[3 * i + 0];
    float dy = coord[3 * j + 1] - coord[3 * i + 1];
    float dz = coord[3 * j + 2] - coord[3 * i + 2];
    float d = sqrtf(dx * dx + dy * dy + dz * dz);
    float fc, dfc;
    if (d < RCR_) {
        float ph = PIF * d / RCR_;
        fc = 0.5f * cosf(ph) + 0.5f;
        dfc = -0.5f * sinf(ph) * (PIF / RCR_);
    } else { fc = 0.f; dfc = 0.f; }
    int spi = spec[i], spj = spec[j];
    const float* gi = daev + (size_t)i * DAEV + spj * 16;
    const float* gj = daev + (size_t)j * DAEV + spi * 16;
    float gs = 0.f;
    #pragma unroll
    for (int k = 0; k < 16; ++k) {
        float sh = 0.8f + 0.275f * k;
        float t = d - sh;
        float ex = expf(-ETAR * t * t);
        float g = gi[k] + gj[k];
        gs += g * 0.25f * ex * (dfc - 2.f * ETAR * t * fc);
    }
    float invd = 1.f / d;
    float gx = gs * dx * invd, gy = gs * dy * invd, gz = gs * dz * invd;
    atomicAdd(&grad[3 * j + 0], gx);  atomicAdd(&grad[3 * j + 1], gy);  atomicAdd(&grad[3 * j + 2], gz);
    atomicAdd(&grad[3 * i + 0], -gx); atomicAdd(&grad[3 * i + 1], -gy); atomicAdd(&grad[3 * i + 2], -gz);
}

// ---------------- AEV angular backward ----------------
__global__ __launch_bounds__(256) void angular_bwd_k(
    const int* __restrict__ tri, const int* __restrict__ spec,
    const float* __restrict__ coord, const float* __restrict__ daev,
    float* __restrict__ grad, int T)
{
    int t = blockIdx.x * blockDim.x + threadIdx.x;
    if (t >= T) return;
    int c = tri[t], a = tri[T + t], b = tri[2 * T + t];
    float cx = coord[3 * c], cy = coord[3 * c + 1], cz = coord[3 * c + 2];
    float v1x = coord[3 * a] - cx, v1y = coord[3 * a + 1] - cy, v1z = coord[3 * a + 2] - cz;
    float v2x = coord[3 * b] - cx, v2y = coord[3 * b + 1] - cy, v2z = coord[3 * b + 2] - cz;
    float d1 = sqrtf(v1x * v1x + v1y * v1y + v1z * v1z);
    float d2 = sqrtf(v2x * v2x + v2y * v2y + v2z * v2z);
    float u = v1x * v2x + v1y * v2y + v1z * v2z;
    float inv12 = 1.f / (d1 * d2);
    float ca = 0.95f * u * inv12;
    float sa = sqrtf(fmaxf(1.f - ca * ca, 1e-12f));
    float fc1, dfc1, fc2, dfc2;
    if (d1 < RCA_) {
        float ph = PIF * d1 / RCA_;
        fc1 = 0.5f * cosf(ph) + 0.5f;
        dfc1 = -0.5f * sinf(ph) * (PIF / RCA_);
    } else { fc1 = 0.f; dfc1 = 0.f; }
    if (d2 < RCA_) {
        float ph = PIF * d2 / RCA_;
        fc2 = 0.5f * cosf(ph) + 0.5f;
        dfc2 = -0.5f * sinf(ph) * (PIF / RCA_);
    } else { fc2 = 0.f; dfc2 = 0.f; }
    float fcj = fc1 * fc2;
    float savg = 0.5f * (d1 + d2);
    int s1 = spec[a], s2 = spec[b];
    int lo = min(s1, s2), hi = max(s1, s2);
    int pidx = lo * SPEC - (lo * (lo - 1)) / 2 + (hi - lo);
    const float* gb = daev + (size_t)c * DAEV + RADN + pidx * 32;
    const float CZ[4] = {0.92387953f, 0.38268343f, -0.38268343f, -0.92387953f};
    const float SZ[4] = {0.38268343f, 0.92387953f, 0.92387953f, 0.38268343f};
    float f1[4], df1[4];
    #pragma unroll
    for (int zz = 0; zz < 4; ++zz) {
        float cd = ca * CZ[zz] + sa * SZ[zz];
        float sd = sa * CZ[zz] - ca * SZ[zz];
        float base = fmaxf(0.5f * (1.f + cd), 0.f);
        float pm1 = powf(base, ZETA_ - 1.f);
        f1[zz] = pm1 * base;
        df1[zz] = ZETA_ * pm1 * (-0.5f * sd);
    }
    float A_ = 0.f, B_ = 0.f, Cc = 0.f;
    #pragma unroll
    for (int q = 0; q < 8; ++q) {
        float sh = 0.8f + 0.3375f * q;
        float tq = savg - sh;
        float f2 = expf(-ETAA * tq * tq);
        float df2 = -ETAA * tq * f2;
        #pragma unroll
        for (int zz = 0; zz < 4; ++zz) {
            float G2 = 2.f * gb[q * 4 + zz];
            A_ += G2 * f2 * df1[zz];
            B_ += G2 * df2 * f1[zz];
            Cc += G2 * f2 * f1[zz];
        }
    }
    A_ *= fcj; B_ *= fcj;
    float C1 = Cc * dfc1 * fc2;
    float C2 = Cc * fc1 * dfc2;
    float cA = -A_ / sa;
    float k12 = cA * 0.95f * inv12;
    float coef1 = (cA * (-ca) / d1 + B_ + C1) / d1;
    float coef2 = (cA * (-ca) / d2 + B_ + C2) / d2;
    float g1x = coef1 * v1x + k12 * v2x;
    float g1y = coef1 * v1y + k12 * v2y;
    float g1z = coef1 * v1z + k12 * v2z;
    float g2x = coef2 * v2x + k12 * v1x;
    float g2y = coef2 * v2y + k12 * v1y;
    float g2z = coef2 * v2z + k12 * v1z;
    atomicAdd(&grad[3 * a + 0], g1x); atomicAdd(&grad[3 * a + 1], g1y); atomicAdd(&grad[3 * a + 2], g1z);
    atomicAdd(&grad[3 * b + 0], g2x); atomicAdd(&grad[3 * b + 1], g2y); atomicAdd(&grad[3 * b + 2], g2z);
    atomicAdd(&grad[3 * c + 0], -(g1x + g2x));
    atomicAdd(&grad[3 * c + 1], -(g1y + g2y));
    atomicAdd(&grad[3 * c + 2], -(g1z + g2z));
}

// ---------------- finalize: forces out, SAE into E ----------------
__global__ __launch_bounds__(256) void finalize_k(
    const float* __restrict__ grad, const int* __restrict__ sgp,
    const float* __restrict__ sae, float* __restrict__ out, int N)
{
    int n = blockIdx.x * blockDim.x + threadIdx.x;
    __shared__ float bs;
    if (threadIdx.x == 0) bs = 0.f;
    __syncthreads();
    float v = 0.f;
    if (n < N) {
        out[1 + 3 * n + 0] = -grad[3 * n + 0];
        out[1 + 3 * n + 1] = -grad[3 * n + 1];
        out[1 + 3 * n + 2] = -grad[3 * n + 2];
        int g = sgp[n];
        if (g >= 0) v = sae[g];
    }
    atomicAdd(&bs, v);
    __syncthreads();
    if (threadIdx.x == 0) atomicAdd(out, bs);
}

// ---------------- host launch ----------------
extern "C" void kernel_launch(void* const* d_in, const int* in_sizes, int n_in,
                              void* d_out, int out_size, void* d_ws, size_t ws_size,
                              hipStream_t stream)
{
    (void)n_in; (void)out_size; (void)ws_size;
    const int* species = (const int*)d_in[0];
    const float* coords = (const float*)d_in[1];
    const int* ai12 = (const int*)d_in[2];
    const int* tri = (const int*)d_in[3];
    const int* sgp = (const int*)d_in[4];
    const float* W1 = (const float*)d_in[5];
    const float* b1 = (const float*)d_in[6];
    const float* W2 = (const float*)d_in[7];
    const float* b2 = (const float*)d_in[8];
    const float* W3 = (const float*)d_in[9];
    const float* b3 = (const float*)d_in[10];
    const float* W4 = (const float*)d_in[11];
    const float* b4 = (const float*)d_in[12];
    const float* sae = (const float*)d_in[13];
    float* out = (float*)d_out;

    const int N = in_sizes[0];
    const int P = in_sizes[2] / 2;
    const int T = in_sizes[3] / 3;

    float* ws = (float*)d_ws;
    size_t off = 0;
    float* aev  = ws + off; off += (size_t)N * DAEV;
    float* daev = ws + off; off += (size_t)N * DAEV;
    float* H1b  = ws + off; off += (size_t)MENS * N * H1W;
    float* H2b  = ws + off; off += (size_t)MENS * N * H2W;
    float* H3b  = ws + off; off += (size_t)MENS * N * H3W;
    float* grad = ws + off; off += (size_t)N * 3;
    int* counts = (int*)(ws + off); off += 8;
    int* lists  = (int*)(ws + off); off += (size_t)SPEC * N;

    hipMemsetAsync(aev, 0, (size_t)N * DAEV * 2 * sizeof(float), stream);
    hipMemsetAsync(grad, 0, (size_t)N * 3 * sizeof(float), stream);
    hipMemsetAsync(counts, 0, 8 * sizeof(int), stream);
    hipMemsetAsync(d_out, 0, sizeof(float), stream);

    build_lists_k<<<(N + 255) / 256, 256, 0, stream>>>(sgp, counts, lists, N);
    radial_fwd_k<<<(P + 255) / 256, 256, 0, stream>>>(ai12, species, coords, aev, P);
    angular_fwd_k<<<(T + 255) / 256, 256, 0, stream>>>(tri, species, coords, aev, T);

    const int rowTiles = (N + 63) / 64;
    // L1 fwd: H1 = celu(AEV @ W1 + b1)
    mgemm_k<MODE_FWD, false, false><<<dim3(2, rowTiles, 56), 256, 0, stream>>>(
        aev, W1, b1, H1b, lists, counts, N, DAEV, H1W, DAEV, H1W, H1W,
        0, (size_t)DAEV * H1W, (size_t)N * H1W);
    // L2 fwd
    mgemm_k<MODE_FWD, false, false><<<dim3(2, rowTiles, 56), 256, 0, stream>>>(
        H1b, W2, b2, H2b, lists, counts, N, H1W, H2W, H1W, H2W, H2W,
        (size_t)N * H1W, (size_t)H1W * H2W, (size_t)N * H2W);
    // L3 fwd
    mgemm_k<MODE_FWD, false, false><<<dim3(2, rowTiles, 56), 256, 0, stream>>>(
        H2b, W3, b3, H3b, lists, counts, N, H2W, H3W, H2W, H3W, H3W,
        (size_t)N * H2W, (size_t)H2W * H3W, (size_t)N * H3W);
    // L4: e = h3.W4 + b4 -> E; dh3 (in place in H3b)
    l4_k<<<dim3((N + 31) / 32, 56), 256, 0, stream>>>(H3b, W4, b4, lists, counts, out, N);
    // L3 bwd: dh2 = (dh3 @ W3^T) * celu'(z2)
    mgemm_k<MODE_BWD, true, false><<<dim3(2, rowTiles, 56), 256, 0, stream>>>(
        H3b, W3, nullptr, H2b, lists, counts, N, H3W, H2W, H3W, H3W, H2W,
        (size_t)N * H3W, (size_t)H2W * H3W, (size_t)N * H2W);
    // L2 bwd: dh1 = (dh2 @ W2^T) * celu'(z1)
    mgemm_k<MODE_BWD, true, false><<<dim3(2, rowTiles, 56), 256, 0, stream>>>(
        H2b, W2, nullptr, H1b, lists, counts, N, H2W, H1W, H2W, H2W, H1W,
        (size_t)N * H2W, (size_t)H1W * H2W, (size_t)N * H1W);
    // L1 bwd (m-concat K=2048): daev = sum_m dh1[m] @ W1[m,s]^T
    mgemm_k<MODE_PLAIN, true, true><<<dim3(8, rowTiles, 7), 256, 0, stream>>>(
        H1b, W1, nullptr, daev, lists, counts, N, MENS * H1W, DAEV, 0, 0, DAEV,
        0, 0, 0);

    radial_bwd_k<<<(P + 255) / 256, 256, 0, stream>>>(ai12, species, coords, daev, grad, P);
    angular_bwd_k<<<(T + 255) / 256, 256, 0, stream>>>(tri, species, coords, daev, grad, T);
    finalize_k<<<(N + 255) / 256, 256, 0, stream>>>(grad, sgp, sae, out, N);
}